// Round 5
// baseline (337.387 us; speedup 1.0000x reference)
//
#include <hip/hip_runtime.h>

#define NN 100000
#define NE 800000
#define IND 64
#define HID 96
#define NL 3
#define NC 512
#define BN_EPS 1e-5f

typedef __attribute__((ext_vector_type(8))) short bf16x8;
typedef __attribute__((ext_vector_type(4))) float f32x4;

static __device__ __forceinline__ float b2f(ushort u) {
    union { uint i; float f; } v; v.i = ((uint)u) << 16; return v.f;
}
static __device__ __forceinline__ ushort f2b(float f) {
    union { float f; uint i; } v; v.f = f;
    uint r = v.i + 0x7FFFu + ((v.i >> 16) & 1u);
    return (ushort)(r >> 16);
}
static __device__ __forceinline__ uint pack2(float a, float b) {
    return (uint)f2b(a) | ((uint)f2b(b) << 16);
}

// ---- weight prep (merged): frag-ordered bf16 for embed + 3 layers ----
// dst[((kt*6+ct)*64+lane)*8+j] = W[kt*32+(lane>>4)*8+j][ct*16+(lane&15)]
static __device__ __forceinline__ void prep_one(const float* srcA, const float* srcB,
                                                ushort* dst, int t) {
    int lane = t & 63;
    int ct = (t >> 6) % 6;
    int kt = t / (6 * 64);
    int k0 = kt * 32 + (lane >> 4) * 8;
    int col = ct * 16 + (lane & 15);
    ushort tmp[8];
#pragma unroll
    for (int j = 0; j < 8; ++j) {
        int k = k0 + j;
        const float* src = (srcB == nullptr || k < 96) ? srcA : srcB;
        int kk = (srcB == nullptr || k < 96) ? k : k - 96;
        tmp[j] = f2b(src[kk * HID + col]);
    }
    uint* od = (uint*)(dst + (size_t)t * 8);
    od[0] = (uint)tmp[0] | ((uint)tmp[1] << 16);
    od[1] = (uint)tmp[2] | ((uint)tmp[3] << 16);
    od[2] = (uint)tmp[4] | ((uint)tmp[5] << 16);
    od[3] = (uint)tmp[6] | ((uint)tmp[7] << 16);
}

__global__ void k_prep_all(const float* __restrict__ W_emb,
                           const float* __restrict__ conv_wl,
                           const float* __restrict__ conv_wr,
                           ushort* __restrict__ Bfe, ushort* __restrict__ Bfl) {
    int b = blockIdx.x;
    if (b < 3) {                       // embed: 2 ktiles -> 768 frags
        int t = b * 256 + threadIdx.x;
        if (t < 2 * 6 * 64) prep_one(W_emb, nullptr, Bfe, t);
    } else {                           // layers: 6 ktiles -> 2304 frags each
        int l = (b - 3) / 9, bb = (b - 3) % 9;
        int t = bb * 256 + threadIdx.x;
        if (t < 6 * 6 * 64)
            prep_one(conv_wl + (size_t)l * 9216, conv_wr + (size_t)l * 9216,
                     Bfl + (size_t)l * 18432, t);
    }
}

// ---- embedding: h = relu(x @ W_emb + b_emb), bf16 out, MFMA ----
__global__ __launch_bounds__(256, 4) void k_embed(const float* __restrict__ x,
        const ushort* __restrict__ Bf, const float* __restrict__ bias,
        ushort* __restrict__ h) {
    __shared__ __align__(16) char smem[24576];
    ushort* sB = (ushort*)smem;          // 12288 B
    ushort* sT = (ushort*)smem;          // reused after sync: 128*96 (24576 B)
    const int tid = threadIdx.x;
    for (int i = tid; i < 768; i += 256) ((uint4*)sB)[i] = ((const uint4*)Bf)[i];
    __syncthreads();
    const int wave = tid >> 6, lane = tid & 63;
    const int rowb = wave * 32;
    const int row0 = blockIdx.x * 128 + rowb;
    const int kof = (lane >> 4) * 8;
    f32x4 acc[2][6];
#pragma unroll
    for (int t = 0; t < 2; ++t)
#pragma unroll
        for (int c = 0; c < 6; ++c) acc[t][c] = (f32x4){0.f, 0.f, 0.f, 0.f};
#pragma unroll
    for (int kt = 0; kt < 2; ++kt) {
        int kk = kt * 32 + kof;
        bf16x8 a[2];
#pragma unroll
        for (int t = 0; t < 2; ++t) {
            int r = row0 + t * 16 + (lane & 15);
            if (r >= NN) r = NN - 1;
            const float* src = x + (size_t)r * IND + kk;
            float4 f0 = *(const float4*)src;
            float4 f1 = *(const float4*)(src + 4);
            a[t][0] = (short)f2b(f0.x); a[t][1] = (short)f2b(f0.y);
            a[t][2] = (short)f2b(f0.z); a[t][3] = (short)f2b(f0.w);
            a[t][4] = (short)f2b(f1.x); a[t][5] = (short)f2b(f1.y);
            a[t][6] = (short)f2b(f1.z); a[t][7] = (short)f2b(f1.w);
        }
#pragma unroll
        for (int ct = 0; ct < 6; ++ct) {
            bf16x8 bb = *(const bf16x8*)&sB[((kt * 6 + ct) * 64 + lane) * 8];
            acc[0][ct] = __builtin_amdgcn_mfma_f32_16x16x32_bf16(a[0], bb, acc[0][ct], 0, 0, 0);
            acc[1][ct] = __builtin_amdgcn_mfma_f32_16x16x32_bf16(a[1], bb, acc[1][ct], 0, 0, 0);
        }
    }
    __syncthreads();
#pragma unroll
    for (int t = 0; t < 2; ++t)
#pragma unroll
        for (int ct = 0; ct < 6; ++ct) {
            int col = ct * 16 + (lane & 15);
            float bv = bias[col];
#pragma unroll
            for (int i = 0; i < 4; ++i) {
                int rb = rowb + t * 16 + (lane >> 4) * 4 + i;
                float v = acc[t][ct][i] + bv;
                sT[rb * HID + col] = f2b(v > 0.f ? v : 0.f);
            }
        }
    __syncthreads();
    for (int i = tid; i < 1536; i += 256) {
        int r = i / 12;
        int g = blockIdx.x * 128 + r;
        if (g < NN) ((uint4*)(h + (size_t)g * HID))[i % 12] = ((uint4*)sT)[i];
    }
}

// ---------------- CSR build ----------------
__global__ void k_hist(const int* __restrict__ ei, int* __restrict__ hist) {
    int e = blockIdx.x * blockDim.x + threadIdx.x;
    if (e < NE) atomicAdd(&hist[ei[NE + e]], 1);
}

__global__ __launch_bounds__(1024) void k_scan1(const int* __restrict__ hist,
        int* __restrict__ rp, int* __restrict__ bsum) {
    __shared__ int sd[1024];
    const int tid = threadIdx.x;
    const int i = blockIdx.x * 1024 + tid;
    int v = (i < NN) ? hist[i] : 0;
    sd[tid] = v;
    __syncthreads();
    for (int off = 1; off < 1024; off <<= 1) {
        int t = (tid >= off) ? sd[tid - off] : 0;
        __syncthreads();
        sd[tid] += t;
        __syncthreads();
    }
    if (i < NN) rp[i] = sd[tid] - v;
    if (tid == 1023) bsum[blockIdx.x] = sd[1023];
}

__global__ __launch_bounds__(128) void k_scan2(const int* __restrict__ bsum,
                                               int* __restrict__ boff) {
    __shared__ int sd[128];
    const int tid = threadIdx.x;
    const int NB = (NN + 1023) / 1024;
    int v = (tid < NB) ? bsum[tid] : 0;
    sd[tid] = v;
    __syncthreads();
    for (int off = 1; off < 128; off <<= 1) {
        int t = (tid >= off) ? sd[tid - off] : 0;
        __syncthreads();
        sd[tid] += t;
        __syncthreads();
    }
    if (tid < NB) boff[tid] = sd[tid] - v;
}

__global__ __launch_bounds__(1024) void k_scan3(int* __restrict__ rp,
        const int* __restrict__ boff) {
    const int i = blockIdx.x * 1024 + threadIdx.x;
    if (i < NN) rp[i] += boff[blockIdx.x];
    if (i == 0) rp[NN] = NE;
}

__global__ void k_fill(const int* __restrict__ ei, int* __restrict__ cursor,
                       int* __restrict__ col) {
    int e = blockIdx.x * blockDim.x + threadIdx.x;
    if (e < NE) {
        int d = ei[NE + e];
        int pos = atomicAdd(&cursor[d], 1);
        col[pos] = ei[e];
    }
}

// ---- mean aggregation: wave-per-node, 4 edges in parallel x2 unroll,
//      BN(prev)+ReLU fused on gather ----
__global__ __launch_bounds__(256) void k_agg(const ushort* __restrict__ pre,
        const int* __restrict__ rp, const int* __restrict__ col,
        const float* __restrict__ stats, const float* __restrict__ gamma,
        const float* __restrict__ beta, ushort* __restrict__ agg) {
    __shared__ float sc[96], sh[96];
    const int tid = threadIdx.x;
    if (tid < 96) {
        float scv = 1.f, shv = 0.f;
        if (stats) {
            float mean = stats[tid] * (1.f / NN);
            float var  = stats[96 + tid] * (1.f / NN) - mean * mean;
            float s = gamma[tid] * rsqrtf(var + BN_EPS);
            scv = s; shv = beta[tid] - mean * s;
        }
        sc[tid] = scv; sh[tid] = shv;
    }
    __syncthreads();
    const int wave = tid >> 6, lane = tid & 63;
    const int feat = lane & 15, eslot = lane >> 4;
    const int n = blockIdx.x * 4 + wave;
    if (n >= NN) return;
    const float s0a = sc[2*feat],      h0a = sh[2*feat];
    const float s0b = sc[2*feat + 1],  h0b = sh[2*feat + 1];
    const float s1a = sc[2*feat + 32], h1a = sh[2*feat + 32];
    const float s1b = sc[2*feat + 33], h1b = sh[2*feat + 33];
    const float s2a = sc[2*feat + 64], h2a = sh[2*feat + 64];
    const float s2b = sc[2*feat + 65], h2b = sh[2*feat + 65];
    const int e0 = rp[n], e1 = rp[n + 1];
    float a0 = 0.f, a1 = 0.f, a2 = 0.f, a3 = 0.f, a4 = 0.f, a5 = 0.f;
    const uint* hu = (const uint*)pre;
    int e = e0 + eslot;
    while (e < e1) {
        int eb = e + 4;
        bool vb = eb < e1;
        int ca = col[e];
        int cb = col[vb ? eb : e];
        const uint* ra = hu + (size_t)ca * 48 + feat;
        const uint* rb = hu + (size_t)cb * 48 + feat;
        uint ua0 = ra[0], ua1 = ra[16], ua2 = ra[32];
        uint ub0 = rb[0], ub1 = rb[16], ub2 = rb[32];
        a0 += fmaxf(b2f((ushort)ua0)         * s0a + h0a, 0.f);
        a1 += fmaxf(b2f((ushort)(ua0 >> 16)) * s0b + h0b, 0.f);
        a2 += fmaxf(b2f((ushort)ua1)         * s1a + h1a, 0.f);
        a3 += fmaxf(b2f((ushort)(ua1 >> 16)) * s1b + h1b, 0.f);
        a4 += fmaxf(b2f((ushort)ua2)         * s2a + h2a, 0.f);
        a5 += fmaxf(b2f((ushort)(ua2 >> 16)) * s2b + h2b, 0.f);
        float m = vb ? 1.f : 0.f;
        a0 += m * fmaxf(b2f((ushort)ub0)         * s0a + h0a, 0.f);
        a1 += m * fmaxf(b2f((ushort)(ub0 >> 16)) * s0b + h0b, 0.f);
        a2 += m * fmaxf(b2f((ushort)ub1)         * s1a + h1a, 0.f);
        a3 += m * fmaxf(b2f((ushort)(ub1 >> 16)) * s1b + h1b, 0.f);
        a4 += m * fmaxf(b2f((ushort)ub2)         * s2a + h2a, 0.f);
        a5 += m * fmaxf(b2f((ushort)(ub2 >> 16)) * s2b + h2b, 0.f);
        e += 8;
    }
    // reduce across the 4 edge-slots (lane bits 4,5)
    a0 += __shfl_xor(a0, 16); a0 += __shfl_xor(a0, 32);
    a1 += __shfl_xor(a1, 16); a1 += __shfl_xor(a1, 32);
    a2 += __shfl_xor(a2, 16); a2 += __shfl_xor(a2, 32);
    a3 += __shfl_xor(a3, 16); a3 += __shfl_xor(a3, 32);
    a4 += __shfl_xor(a4, 16); a4 += __shfl_xor(a4, 32);
    a5 += __shfl_xor(a5, 16); a5 += __shfl_xor(a5, 32);
    if (eslot == 0) {
        int d = e1 - e0; if (d < 1) d = 1;
        float inv = 1.0f / (float)d;
        uint* ar = (uint*)agg + (size_t)n * 48 + feat;
        ar[0]  = pack2(a0 * inv, a1 * inv);
        ar[16] = pack2(a2 * inv, a3 * inv);
        ar[32] = pack2(a4 * inv, a5 * inv);
    }
}

// ---- layer GEMM: hnew = [agg | norm_prev(pre)] @ [[wl],[wr]] + bl, fused BN stats ----
__global__ __launch_bounds__(256, 4) void k_gemm(const ushort* __restrict__ aggb,
        const ushort* __restrict__ pre, const ushort* __restrict__ Bf,
        const float* __restrict__ bl, ushort* __restrict__ hnew,
        float* __restrict__ stats,
        const float* __restrict__ statsP, const float* __restrict__ gammaP,
        const float* __restrict__ betaP) {
    __shared__ __align__(16) char smem[40704];
    ushort* sB = (ushort*)smem;                    // 36864 B
    ushort* sT = (ushort*)smem;                    // reused after sync (24576 B)
    float*  sredS = (float*)(smem + 36864);        // 384 floats
    float*  sredQ = (float*)(smem + 38400);        // 384 floats
    float2* sscsh = (float2*)(smem + 39936);       // 96 float2
    const int tid = threadIdx.x;
    for (int i = tid; i < 2304; i += 256) ((uint4*)sB)[i] = ((const uint4*)Bf)[i];
    if (tid < 96) {
        float scv = 1.f, shv = 0.f;
        if (statsP) {
            float mean = statsP[tid] * (1.f / NN);
            float var  = statsP[96 + tid] * (1.f / NN) - mean * mean;
            float s = gammaP[tid] * rsqrtf(var + BN_EPS);
            scv = s; shv = betaP[tid] - mean * s;
        }
        sscsh[tid] = make_float2(scv, shv);
    }
    __syncthreads();
    const int wave = tid >> 6, lane = tid & 63;
    const int rowb = wave * 32;
    const int row0 = blockIdx.x * 128 + rowb;
    const int kof = (lane >> 4) * 8;
    f32x4 acc[2][6];
#pragma unroll
    for (int t = 0; t < 2; ++t)
#pragma unroll
        for (int c = 0; c < 6; ++c) acc[t][c] = (f32x4){0.f, 0.f, 0.f, 0.f};
#pragma unroll
    for (int kt = 0; kt < 6; ++kt) {
        bf16x8 a[2];
#pragma unroll
        for (int t = 0; t < 2; ++t) {
            int r = row0 + t * 16 + (lane & 15);
            if (r >= NN) r = NN - 1;
            if (kt < 3) {
                int kk = kt * 32 + kof;
                a[t] = *(const bf16x8*)(aggb + (size_t)r * HID + kk);
            } else {
                int kk = (kt - 3) * 32 + kof;
                bf16x8 raw = *(const bf16x8*)(pre + (size_t)r * HID + kk);
                union { bf16x8 h; uint u[4]; } pk;
#pragma unroll
                for (int j = 0; j < 4; ++j) {
                    float2 p0 = sscsh[kk + 2*j];
                    float2 p1 = sscsh[kk + 2*j + 1];
                    float v0 = fmaxf(b2f((ushort)raw[2*j])     * p0.x + p0.y, 0.f);
                    float v1 = fmaxf(b2f((ushort)raw[2*j + 1]) * p1.x + p1.y, 0.f);
                    pk.u[j] = pack2(v0, v1);
                }
                a[t] = pk.h;
            }
        }
#pragma unroll
        for (int ct = 0; ct < 6; ++ct) {
            bf16x8 bb = *(const bf16x8*)&sB[((kt * 6 + ct) * 64 + lane) * 8];
            acc[0][ct] = __builtin_amdgcn_mfma_f32_16x16x32_bf16(a[0], bb, acc[0][ct], 0, 0, 0);
            acc[1][ct] = __builtin_amdgcn_mfma_f32_16x16x32_bf16(a[1], bb, acc[1][ct], 0, 0, 0);
        }
    }
    __syncthreads();
    float s[6], q[6];
#pragma unroll
    for (int c = 0; c < 6; ++c) { s[c] = 0.f; q[c] = 0.f; }
#pragma unroll
    for (int t = 0; t < 2; ++t)
#pragma unroll
        for (int ct = 0; ct < 6; ++ct) {
            int col = ct * 16 + (lane & 15);
            float bv = bl[col];
#pragma unroll
            for (int i = 0; i < 4; ++i) {
                int rb = rowb + t * 16 + (lane >> 4) * 4 + i;
                int g = blockIdx.x * 128 + rb;
                float v = acc[t][ct][i] + bv;
                if (g < NN) { s[ct] += v; q[ct] += v * v; }
                sT[rb * HID + col] = f2b(v);
            }
        }
#pragma unroll
    for (int c = 0; c < 6; ++c) {
        s[c] += __shfl_xor(s[c], 16); s[c] += __shfl_xor(s[c], 32);
        q[c] += __shfl_xor(q[c], 16); q[c] += __shfl_xor(q[c], 32);
    }
    if (lane < 16) {
#pragma unroll
        for (int c = 0; c < 6; ++c) {
            sredS[wave * 96 + c * 16 + lane] = s[c];
            sredQ[wave * 96 + c * 16 + lane] = q[c];
        }
    }
    __syncthreads();
    if (tid < 96) {
        float S = sredS[tid] + sredS[96 + tid] + sredS[192 + tid] + sredS[288 + tid];
        float Q = sredQ[tid] + sredQ[96 + tid] + sredQ[192 + tid] + sredQ[288 + tid];
        atomicAdd(&stats[tid], S);
        atomicAdd(&stats[96 + tid], Q);
    }
    for (int i = tid; i < 1536; i += 256) {
        int r = i / 12;
        int g = blockIdx.x * 128 + r;
        if (g < NN) ((uint4*)(hnew + (size_t)g * HID))[i % 12] = ((uint4*)sT)[i];
    }
}

// ---------------- central-node MLP head (final BN+ReLU fused) ----------------
__global__ __launch_bounds__(128) void k_mlp(const ushort* __restrict__ pre,
        const int* __restrict__ cidx, const float* __restrict__ stats,
        const float* __restrict__ gamma, const float* __restrict__ beta,
        const float* __restrict__ W1, const float* __restrict__ b1,
        const float* __restrict__ W2, const float* __restrict__ b2,
        float* __restrict__ out) {
    __shared__ float nh[96];
    __shared__ float hid[96];
    __shared__ float red[128];
    const int c = blockIdx.x;
    const int node = cidx[c];
    const int tid = threadIdx.x;
    if (tid < 96) {
        float mean = stats[tid] * (1.f / NN);
        float var  = stats[96 + tid] * (1.f / NN) - mean * mean;
        float s = gamma[tid] * rsqrtf(var + BN_EPS);
        float v = b2f(pre[(size_t)node * 96 + tid]) * s + (beta[tid] - mean * s);
        nh[tid] = fmaxf(v, 0.f);
    }
    __syncthreads();
    if (tid < 96) {
        float a = 0.f;
        for (int k = 0; k < 96; ++k) a += nh[k] * W1[k * 96 + tid];
        hid[tid] = fmaxf(a + b1[tid], 0.f);
    }
    __syncthreads();
    red[tid] = (tid < 96) ? hid[tid] * W2[tid] : 0.f;
    __syncthreads();
    for (int off = 64; off > 0; off >>= 1) {
        if (tid < off) red[tid] += red[tid + off];
        __syncthreads();
    }
    if (tid == 0) out[c] = red[0] + b2[0];
}

extern "C" void kernel_launch(void* const* d_in, const int* in_sizes, int n_in,
                              void* d_out, int out_size, void* d_ws, size_t ws_size,
                              hipStream_t stream) {
    const float* x        = (const float*)d_in[0];
    const int*   ei       = (const int*)d_in[1];
    const int*   cidx     = (const int*)d_in[3];
    const float* W_emb    = (const float*)d_in[4];
    const float* b_emb    = (const float*)d_in[5];
    const float* conv_wl  = (const float*)d_in[6];
    const float* conv_bl  = (const float*)d_in[7];
    const float* conv_wr  = (const float*)d_in[8];
    const float* bn_gamma = (const float*)d_in[9];
    const float* bn_beta  = (const float*)d_in[10];
    const float* W1       = (const float*)d_in[11];
    const float* b1       = (const float*)d_in[12];
    const float* W2       = (const float*)d_in[13];
    const float* b2       = (const float*)d_in[14];
    float* out = (float*)d_out;

    char* ws = (char*)d_ws;
    size_t off = 0;
    auto alloc = [&](size_t bytes) -> void* {
        void* p = ws + off;
        off = (off + bytes + 255) & ~(size_t)255;
        return p;
    };
    ushort* h    = (ushort*)alloc((size_t)NN * 96 * 2);
    ushort* hnew = (ushort*)alloc((size_t)NN * 96 * 2);
    ushort* agg  = (ushort*)alloc((size_t)NN * 96 * 2);
    int*   hist  = (int*)alloc((size_t)NN * 4);
    int*   rp    = (int*)alloc((size_t)(NN + 1) * 4);
    int*   curs  = (int*)alloc((size_t)NN * 4);
    int*   col   = (int*)alloc((size_t)NE * 4);
    int*   bsum  = (int*)alloc(128 * 4);
    int*   boff  = (int*)alloc(128 * 4);
    float* stats = (float*)alloc((size_t)NL * 192 * 4);
    ushort* Bfe  = (ushort*)alloc((size_t)2 * 6 * 64 * 8 * 2);
    ushort* Bfl  = (ushort*)alloc((size_t)NL * 6 * 6 * 64 * 8 * 2);
    (void)ws_size; (void)in_sizes; (void)n_in; (void)out_size;

    const int NB = (NN + 1023) / 1024;

    hipMemsetAsync(hist, 0, (size_t)NN * 4, stream);
    hipMemsetAsync(stats, 0, (size_t)NL * 192 * 4, stream);

    k_prep_all<<<30, 256, 0, stream>>>(W_emb, conv_wl, conv_wr, Bfe, Bfl);

    k_embed<<<(NN + 127) / 128, 256, 0, stream>>>(x, Bfe, b_emb, h);
    k_hist<<<(NE + 255) / 256, 256, 0, stream>>>(ei, hist);
    k_scan1<<<NB, 1024, 0, stream>>>(hist, rp, bsum);
    k_scan2<<<1, 128, 0, stream>>>(bsum, boff);
    k_scan3<<<NB, 1024, 0, stream>>>(rp, boff);
    hipMemcpyAsync(curs, rp, (size_t)NN * 4, hipMemcpyDeviceToDevice, stream);
    k_fill<<<(NE + 255) / 256, 256, 0, stream>>>(ei, curs, col);

    // ping-pong: src -> dst per layer
    const ushort* src = h;
    ushort* dst = hnew;
    for (int l = 0; l < NL; ++l) {
        const float* stP = (l == 0) ? nullptr : stats + (size_t)(l - 1) * 192;
        const float* gP  = (l == 0) ? nullptr : bn_gamma + (size_t)(l - 1) * 96;
        const float* bP  = (l == 0) ? nullptr : bn_beta + (size_t)(l - 1) * 96;
        k_agg<<<(NN + 3) / 4, 256, 0, stream>>>(src, rp, col, stP, gP, bP, agg);
        k_gemm<<<(NN + 127) / 128, 256, 0, stream>>>(agg, src,
            Bfl + (size_t)l * 18432, conv_bl + (size_t)l * 96, dst,
            stats + (size_t)l * 192, stP, gP, bP);
        const ushort* t = src; src = dst; dst = (ushort*)t;
    }
    k_mlp<<<NC, 128, 0, stream>>>(src, cidx, stats + (size_t)(NL - 1) * 192,
        bn_gamma + (size_t)(NL - 1) * 96, bn_beta + (size_t)(NL - 1) * 96,
        W1, b1, W2, b2, out);
}